// Round 9
// baseline (452.510 us; speedup 1.0000x reference)
//
#include <hip/hip_runtime.h>

// Sizes (fixed): B=16, CIN=512, COUT=512, K=3, H=W=64, STYLE=512, BASIS=8, DIRS=8
// Workspace layout (bytes):
//  xp   (NHWC padded bf16 [16][66][66][512])  @ 0          : 71,368,704
//  wgt  (bf16 [16][9][512][512], NO demod)    @ 71,368,704 : 75,497,472
//  G    (36 floats, padded)                   @ 146,866,176: 256
//  camp ([16][8] f32)                         @ 146,866,432: 512
//  smod ([16][512] f32)                       @ 146,866,944: 32,768
//  demod([16][512] f32)                       @ 146,899,712: 32,768

typedef __attribute__((ext_vector_type(8))) short bf16x8;
typedef __attribute__((ext_vector_type(4))) float f32x4;

__device__ __forceinline__ unsigned short f2bf(float f) {
  unsigned u = __float_as_uint(f);
  return (unsigned short)((u + 0x7FFFu + ((u >> 16) & 1u)) >> 16);
}

__device__ __forceinline__ void gl_lds16(const void* g, void* l) {
  __builtin_amdgcn_global_load_lds(
      (const __attribute__((address_space(1))) void*)g,
      (__attribute__((address_space(3))) void*)l, 16, 0, 0);
}

template <int N> __device__ __forceinline__ void vm_wait() {
  if constexpr (N == 3) asm volatile("s_waitcnt vmcnt(3)" ::: "memory");
  else if constexpr (N == 0) asm volatile("s_waitcnt vmcnt(0)" ::: "memory");
}

// ---- K1: pad + NCHW f32 -> NHWC bf16, borders zeroed in-kernel ----
__global__ __launch_bounds__(256) void k_pad(const float* __restrict__ x,
                                             unsigned short* __restrict__ xp) {
  const int bx = blockIdx.x;
  const int b   = bx >> 9;
  const int rem = bx & 511;
  const int y   = rem >> 3;
  const int cb  = rem & 7;
  const int t = threadIdx.x;
  __shared__ float tile[64][65];
  const float* src = x + ((size_t)(b * 512 + cb * 64) * 4096) + y * 64;
#pragma unroll
  for (int r = 0; r < 4; ++r) {
    int idx = r * 256 + t;
    int ch = idx >> 4;
    int xq = (idx & 15) << 2;
    float4 v = *(const float4*)(src + (size_t)ch * 4096 + xq);
    tile[ch][xq + 0] = v.x; tile[ch][xq + 1] = v.y;
    tile[ch][xq + 2] = v.z; tile[ch][xq + 3] = v.w;
  }
  const uint4 z4 = {0u, 0u, 0u, 0u};
  if (t < 16) {
    const int side = t >> 3;
    const int lo = (t & 7) * 8;
    unsigned short* p =
        xp + (((size_t)(b * 66 + y + 1) * 66 + side * 65) * 512 + cb * 64 + lo);
    *(uint4*)p = z4;
  }
  if (y == 0 || y == 63) {
    const int row = (y == 0) ? 0 : 65;
    for (int idx = t; idx < 528; idx += 256) {
      const int c = idx >> 3;
      const int lo = (idx & 7) * 8;
      unsigned short* p =
          xp + (((size_t)(b * 66 + row) * 66 + c) * 512 + cb * 64 + lo);
      *(uint4*)p = z4;
    }
  }
  __syncthreads();
  const int col = t >> 2;
  const int q = t & 3;
  union { unsigned short u16[16]; uint4 v[2]; } pk;
#pragma unroll
  for (int j = 0; j < 16; ++j) pk.u16[j] = f2bf(tile[q * 16 + j][col]);
  unsigned short* dst =
      xp + (((size_t)(b * 66 + y + 1) * 66 + col + 1) * 512 + cb * 64 + q * 16);
  *(uint4*)dst = pk.v[0];
  *(uint4*)(dst + 8) = pk.v[1];
}

// ---- K2: s[b][i] = style[b] . mod_w[i] + mod_b[i] ----
__global__ __launch_bounds__(256) void k_mod(const float* __restrict__ style,
                                             const float* __restrict__ mod_w,
                                             const float* __restrict__ mod_b,
                                             float* __restrict__ smod) {
  const int b = blockIdx.x;
  __shared__ float st[512];
  for (int d = threadIdx.x; d < 512; d += 256) st[d] = style[b * 512 + d];
  __syncthreads();
  for (int i = threadIdx.x; i < 512; i += 256) {
    const float* wr = mod_w + (size_t)i * 512;
    float acc = 0.f;
#pragma unroll 4
    for (int d = 0; d < 512; d += 4) {
      float4 wv = *(const float4*)(wr + d);
      acc += wv.x * st[d] + wv.y * st[d + 1] + wv.z * st[d + 2] + wv.w * st[d + 3];
    }
    smod[b * 512 + i] = acc + mod_b[i];
  }
}

// ---- K3: Gram matrix of the 8 basis vectors (upper-tri, 36 entries) ----
__global__ __launch_bounds__(256, 3) void k_gram(const float* __restrict__ bv,
                                                 float* __restrict__ G) {
  const int P4 = 589824;  // (512*512*9)/4
  float a[36];
#pragma unroll
  for (int c = 0; c < 36; ++c) a[c] = 0.f;
  const float4* bv4 = (const float4*)bv;
  for (int p = blockIdx.x * 256 + threadIdx.x; p < P4; p += gridDim.x * 256) {
    float4 v[8];
#pragma unroll
    for (int k = 0; k < 8; ++k) v[k] = bv4[(size_t)k * P4 + p];
    int c = 0;
#pragma unroll
    for (int i = 0; i < 8; ++i)
#pragma unroll
      for (int j = i; j < 8; ++j) {
        a[c] += v[i].x * v[j].x + v[i].y * v[j].y + v[i].z * v[j].z +
                v[i].w * v[j].w;
        ++c;
      }
  }
#pragma unroll
  for (int c = 0; c < 36; ++c)
#pragma unroll
    for (int off = 32; off > 0; off >>= 1) a[c] += __shfl_down(a[c], off);
  __shared__ float red[4][36];
  const int wv = threadIdx.x >> 6;
  if ((threadIdx.x & 63) == 0)
#pragma unroll
    for (int c = 0; c < 36; ++c) red[wv][c] = a[c];
  __syncthreads();
  if (threadIdx.x < 36)
    atomicAdd(&G[threadIdx.x], red[0][threadIdx.x] + red[1][threadIdx.x] +
                                   red[2][threadIdx.x] + red[3][threadIdx.x]);
}

// ---- K4: camp[b][k] = coef[b][k] * shift_b / max(||delta||,1e-12) via Gram ----
__global__ void k_amp(const float* __restrict__ shifts_coords,
                      const float* __restrict__ batch_shifts,
                      const int* __restrict__ dirs, const float* __restrict__ G,
                      float* __restrict__ camp) {
  const int b = threadIdx.x;
  if (b < 16) {
    const int dir = dirs[b];
    float c[8];
    for (int k = 0; k < 8; ++k) c[k] = shifts_coords[dir * 8 + k];
    float n2 = 0.f;
    int idx = 0;
    for (int i = 0; i < 8; ++i)
      for (int j = i; j < 8; ++j) {
        float g = G[idx++];
        n2 += (i == j) ? c[i] * c[i] * g : 2.f * c[i] * c[j] * g;
      }
    float nrm = sqrtf(fmaxf(n2, 0.f));
    float amp = batch_shifts[b] / fmaxf(nrm, 1e-12f);
    for (int k = 0; k < 8; ++k) camp[b * 8 + k] = c[k] * amp;
  }
}

// ---- K5: modulated weights -> bf16 [b][kk][o][i]; demod table separate ----
__global__ __launch_bounds__(512) void k_weights(const float* __restrict__ weight,
                                                 const float* __restrict__ bv,
                                                 const float* __restrict__ smod,
                                                 const float* __restrict__ camp,
                                                 unsigned short* __restrict__ wgt,
                                                 float* __restrict__ demod) {
  const int o = blockIdx.x;
  const int i = threadIdx.x;
  __shared__ float cl[128];
  __shared__ float red[8][16];
  if (threadIdx.x < 128) cl[threadIdx.x] = camp[threadIdx.x];
  __syncthreads();
  const float scl = 0.014731391274719738f;  // 1/sqrt(512*9)
  float sm[16];
#pragma unroll
  for (int b = 0; b < 16; ++b) sm[b] = smod[b * 512 + i] * scl;
  float ssq[16];
#pragma unroll
  for (int b = 0; b < 16; ++b) ssq[b] = 0.f;
  const size_t base = ((size_t)o * 512 + i) * 9;
#pragma unroll
  for (int g = 0; g < 3; ++g) {
    float w[3], v[8][3];
#pragma unroll
    for (int q = 0; q < 3; ++q) w[q] = weight[base + g * 3 + q];
#pragma unroll
    for (int k = 0; k < 8; ++k)
#pragma unroll
      for (int q = 0; q < 3; ++q)
        v[k][q] = bv[(size_t)k * 2359296 + base + g * 3 + q];
#pragma unroll
    for (int b = 0; b < 16; ++b) {
#pragma unroll
      for (int q = 0; q < 3; ++q) {
        float d = w[q];
#pragma unroll
        for (int k = 0; k < 8; ++k) d = fmaf(cl[b * 8 + k], v[k][q], d);
        float wv = d * sm[b];
        ssq[b] = fmaf(wv, wv, ssq[b]);
        wgt[(((size_t)(b * 9 + g * 3 + q) * 512 + o) << 9) + i] = f2bf(wv);
      }
    }
  }
#pragma unroll
  for (int b = 0; b < 16; ++b)
#pragma unroll
    for (int off = 32; off > 0; off >>= 1) ssq[b] += __shfl_down(ssq[b], off);
  const int wv_ = threadIdx.x >> 6;
  if ((threadIdx.x & 63) == 0)
#pragma unroll
    for (int b = 0; b < 16; ++b) red[wv_][b] = ssq[b];
  __syncthreads();
  if (threadIdx.x < 16) {
    float s = 0.f;
#pragma unroll
    for (int wq = 0; wq < 8; ++wq) s += red[wq][threadIdx.x];
    demod[threadIdx.x * 512 + o] = rsqrtf(s + 1e-8f);
  }
}

// ---- K6: grouped conv, 256x128 tile, BK=32, triple-buffer 3x24KB = 72KB,
// 2 blocks/CU (16 waves/CU): co-resident blocks overlap each other's stalls.
// Per wave: 64x64 output (acc = 64 regs). Per step: 8 ds_read_b128 +
// 3 gl_lds (depth-2 prefetch) + 16 MFMA + vmcnt(3) + 1 barrier.
// 64B-row swizzle: slot' = slot ^ ((row>>1)&3)  (2 lanes/quad = free).
__global__ __launch_bounds__(512, 4) void k_conv(
    const unsigned short* __restrict__ xp, const unsigned short* __restrict__ wgt,
    const float* __restrict__ demod, float* __restrict__ out) {
  extern __shared__ unsigned char smem[];  // 73728 = 3 x (A 16K | B 8K)
  const int tid = threadIdx.x;
  const int l = tid & 63;
  const int w = tid >> 6;
  const int wr = w >> 1;  // 0..3 -> rows wr*64..+63
  const int wc = w & 1;   // 0..1 -> px  wc*64..+63

  // XCD-bijective swizzle: 1024 blocks, 128/XCD = 2 full samples per XCD
  const int bid = blockIdx.x;
  const int bz = (bid & 7) * 128 + (bid >> 3);
  const int b = bz >> 6;
  const int tt = bz & 63;
  const int o0 = (tt >> 5) << 8;  // 0 / 256
  const int tn = tt & 31;
  const int n0 = tn << 7;  // pixel base (2 rows of 64)
  const int y0 = tn << 1;

  // A staging: chunks idx = r*512+tid (0..1023): row=idx>>2 (0..255), slot=idx&3
  // pre-swizzled source chunk = slot ^ ((row>>1)&3)
  unsigned aOff[2];
#pragma unroll
  for (int r = 0; r < 2; ++r) {
    const int idx = r * 512 + tid;
    const int row = idx >> 2;
    const int sc_ = (idx & 3) ^ ((row >> 1) & 3);
    aOff[r] = ((unsigned)(o0 + row) << 10) + sc_ * 16;
  }
  // B staging: chunks tid (0..511): row(px)=tid>>2 (0..127), slot=tid&3
  unsigned bOff;
  {
    const int row = tid >> 2;
    const int sc_ = (tid & 3) ^ ((row >> 1) & 3);
    bOff = ((unsigned)((b * 66 + y0 + (row >> 6)) * 66 + (row & 63)) << 10) +
           sc_ * 16;
  }

  const char* wgtB = (const char*)wgt + ((size_t)(b * 9) << 19);
  const char* xpc = (const char*)xp;

  auto stage = [&](unsigned char* buf, int kt) {
    const int kk = kt >> 4;  // tap
    const int is = kt & 15;  // 32-channel slice
    const int ky = kk / 3;
    const int kx = kk - ky * 3;
    const unsigned aPl = ((unsigned)kk << 19) + ((unsigned)is << 6);
    const unsigned bPl = ((unsigned)(ky * 66 + kx) << 10) + ((unsigned)is << 6);
#pragma unroll
    for (int r = 0; r < 2; ++r)
      gl_lds16(wgtB + aPl + aOff[r], buf + (r * 512 + tid) * 16);
    gl_lds16(xpc + bPl + bOff, buf + 16384 + tid * 16);
  };

  f32x4 acc[4][4];
  const f32x4 zz = {0.f, 0.f, 0.f, 0.f};
#pragma unroll
  for (int mi = 0; mi < 4; ++mi)
#pragma unroll
    for (int ni = 0; ni < 4; ++ni) acc[mi][ni] = zz;
  bf16x8 af[4], bf[4];

  const int lq = l & 15;
  const int ls = l >> 4;

  unsigned char* p0 = smem;
  unsigned char* p1 = smem + 24576;
  unsigned char* p2 = smem + 49152;
  stage(p0, 0);
  stage(p1, 1);
  vm_wait<3>();
  __builtin_amdgcn_s_barrier();
  __builtin_amdgcn_sched_barrier(0);

#pragma unroll 1
  for (int kt = 0; kt < 144; ++kt) {
    const unsigned char* lA = p0;
    const unsigned char* lB = p0 + 16384;
#pragma unroll
    for (int ni = 0; ni < 4; ++ni) {
      const int row = wc * 64 + ni * 16 + lq;
      bf[ni] = *(const bf16x8*)(lB + row * 64 + ((ls ^ ((row >> 1) & 3)) << 4));
    }
#pragma unroll
    for (int mi = 0; mi < 4; ++mi) {
      const int row = wr * 64 + mi * 16 + lq;
      af[mi] = *(const bf16x8*)(lA + row * 64 + ((ls ^ ((row >> 1) & 3)) << 4));
    }
    if (kt <= 141) stage(p2, kt + 2);  // p2 held kt-1, consumed pre-barrier
    __builtin_amdgcn_s_setprio(1);
#pragma unroll
    for (int mi = 0; mi < 4; ++mi)
#pragma unroll
      for (int ni = 0; ni < 4; ++ni)
        acc[mi][ni] = __builtin_amdgcn_mfma_f32_16x16x32_bf16(
            af[mi], bf[ni], acc[mi][ni], 0, 0, 0);
    __builtin_amdgcn_s_setprio(0);
    __builtin_amdgcn_sched_barrier(0);
    if (kt <= 141) vm_wait<3>();        // kt+1's 3 done; kt+2's 3 in flight
    else if (kt == 142) vm_wait<0>();
    if (kt <= 142) {
      __builtin_amdgcn_s_barrier();
      __builtin_amdgcn_sched_barrier(0);
    }
    unsigned char* tmp = p0; p0 = p1; p1 = p2; p2 = tmp;
  }

  float* outb = out + (size_t)(b * 512 + o0) * 4096 + n0;
#pragma unroll
  for (int mi = 0; mi < 4; ++mi) {
    const int orow = wr * 64 + mi * 16 + ls * 4;
    float dm[4];
#pragma unroll
    for (int r = 0; r < 4; ++r) dm[r] = demod[b * 512 + o0 + orow + r];
#pragma unroll
    for (int ni = 0; ni < 4; ++ni) {
      const int pix = wc * 64 + ni * 16 + lq;
#pragma unroll
      for (int r = 0; r < 4; ++r)
        outb[(size_t)(orow + r) * 4096 + pix] = acc[mi][ni][r] * dm[r];
    }
  }
}

extern "C" void kernel_launch(void* const* d_in, const int* in_sizes, int n_in,
                              void* d_out, int out_size, void* d_ws,
                              size_t ws_size, hipStream_t stream) {
  const float* x      = (const float*)d_in[0];
  const float* style  = (const float*)d_in[1];
  const float* weight = (const float*)d_in[2];
  const float* mod_w  = (const float*)d_in[3];
  const float* mod_b  = (const float*)d_in[4];
  const float* bv     = (const float*)d_in[5];
  const float* sc     = (const float*)d_in[6];
  const float* bsh    = (const float*)d_in[7];
  const int*   bdir   = (const int*)d_in[8];
  float* out = (float*)d_out;

  char* ws = (char*)d_ws;
  unsigned short* xp  = (unsigned short*)(ws);
  unsigned short* wgt = (unsigned short*)(ws + 71368704);
  float* G     = (float*)(ws + 146866176);
  float* camp  = (float*)(ws + 146866432);
  float* smod  = (float*)(ws + 146866944);
  float* demod = (float*)(ws + 146899712);

  hipFuncSetAttribute((const void*)k_conv,
                      hipFuncAttributeMaxDynamicSharedMemorySize, 73728);

  hipMemsetAsync(G, 0, 256, stream);
  k_pad<<<8192, 256, 0, stream>>>(x, xp);
  k_mod<<<16, 256, 0, stream>>>(style, mod_w, mod_b, smod);
  k_gram<<<1024, 256, 0, stream>>>(bv, G);
  k_amp<<<1, 64, 0, stream>>>(sc, bsh, bdir, G, camp);
  k_weights<<<512, 512, 0, stream>>>(weight, bv, smod, camp, wgt, demod);
  k_conv<<<1024, 512, 73728, stream>>>(xp, wgt, demod, out);
}

// Round 10
// 445.031 us; speedup vs baseline: 1.0168x; 1.0168x over previous
//
#include <hip/hip_runtime.h>

// Sizes (fixed): B=16, CIN=512, COUT=512, K=3, H=W=64, STYLE=512, BASIS=8, DIRS=8
// Workspace layout (bytes):
//  xp   (NHWC padded bf16 [16][66][66][512])  @ 0          : 71,368,704
//  wgt  (bf16 [16][9][512][512], NO demod)    @ 71,368,704 : 75,497,472
//  G    (36 floats, padded)                   @ 146,866,176: 256
//  camp ([16][8] f32)                         @ 146,866,432: 512
//  smod ([16][512] f32)                       @ 146,866,944: 32,768
//  demod([16][512] f32)                       @ 146,899,712: 32,768

typedef __attribute__((ext_vector_type(8))) short bf16x8;
typedef __attribute__((ext_vector_type(4))) float f32x4;

__device__ __forceinline__ unsigned short f2bf(float f) {
  unsigned u = __float_as_uint(f);
  return (unsigned short)((u + 0x7FFFu + ((u >> 16) & 1u)) >> 16);
}

__device__ __forceinline__ void gl_lds16(const void* g, void* l) {
  __builtin_amdgcn_global_load_lds(
      (const __attribute__((address_space(1))) void*)g,
      (__attribute__((address_space(3))) void*)l, 16, 0, 0);
}

template <int N> __device__ __forceinline__ void vm_wait() {
  if constexpr (N == 6) asm volatile("s_waitcnt vmcnt(6)" ::: "memory");
  else if constexpr (N == 0) asm volatile("s_waitcnt vmcnt(0)" ::: "memory");
}

// ---- K1: pad + NCHW f32 -> NHWC bf16, borders zeroed in-kernel ----
__global__ __launch_bounds__(256) void k_pad(const float* __restrict__ x,
                                             unsigned short* __restrict__ xp) {
  const int bx = blockIdx.x;
  const int b   = bx >> 9;
  const int rem = bx & 511;
  const int y   = rem >> 3;
  const int cb  = rem & 7;
  const int t = threadIdx.x;
  __shared__ float tile[64][65];
  const float* src = x + ((size_t)(b * 512 + cb * 64) * 4096) + y * 64;
#pragma unroll
  for (int r = 0; r < 4; ++r) {
    int idx = r * 256 + t;
    int ch = idx >> 4;
    int xq = (idx & 15) << 2;
    float4 v = *(const float4*)(src + (size_t)ch * 4096 + xq);
    tile[ch][xq + 0] = v.x; tile[ch][xq + 1] = v.y;
    tile[ch][xq + 2] = v.z; tile[ch][xq + 3] = v.w;
  }
  const uint4 z4 = {0u, 0u, 0u, 0u};
  if (t < 16) {
    const int side = t >> 3;
    const int lo = (t & 7) * 8;
    unsigned short* p =
        xp + (((size_t)(b * 66 + y + 1) * 66 + side * 65) * 512 + cb * 64 + lo);
    *(uint4*)p = z4;
  }
  if (y == 0 || y == 63) {
    const int row = (y == 0) ? 0 : 65;
    for (int idx = t; idx < 528; idx += 256) {
      const int c = idx >> 3;
      const int lo = (idx & 7) * 8;
      unsigned short* p =
          xp + (((size_t)(b * 66 + row) * 66 + c) * 512 + cb * 64 + lo);
      *(uint4*)p = z4;
    }
  }
  __syncthreads();
  const int col = t >> 2;
  const int q = t & 3;
  union { unsigned short u16[16]; uint4 v[2]; } pk;
#pragma unroll
  for (int j = 0; j < 16; ++j) pk.u16[j] = f2bf(tile[q * 16 + j][col]);
  unsigned short* dst =
      xp + (((size_t)(b * 66 + y + 1) * 66 + col + 1) * 512 + cb * 64 + q * 16);
  *(uint4*)dst = pk.v[0];
  *(uint4*)(dst + 8) = pk.v[1];
}

// ---- K2: s[b][i] = style[b] . mod_w[i] + mod_b[i] ----
__global__ __launch_bounds__(256) void k_mod(const float* __restrict__ style,
                                             const float* __restrict__ mod_w,
                                             const float* __restrict__ mod_b,
                                             float* __restrict__ smod) {
  const int b = blockIdx.x;
  __shared__ float st[512];
  for (int d = threadIdx.x; d < 512; d += 256) st[d] = style[b * 512 + d];
  __syncthreads();
  for (int i = threadIdx.x; i < 512; i += 256) {
    const float* wr = mod_w + (size_t)i * 512;
    float acc = 0.f;
#pragma unroll 4
    for (int d = 0; d < 512; d += 4) {
      float4 wv = *(const float4*)(wr + d);
      acc += wv.x * st[d] + wv.y * st[d + 1] + wv.z * st[d + 2] + wv.w * st[d + 3];
    }
    smod[b * 512 + i] = acc + mod_b[i];
  }
}

// ---- K3: Gram matrix of the 8 basis vectors (upper-tri, 36 entries) ----
__global__ __launch_bounds__(256, 3) void k_gram(const float* __restrict__ bv,
                                                 float* __restrict__ G) {
  const int P4 = 589824;  // (512*512*9)/4
  float a[36];
#pragma unroll
  for (int c = 0; c < 36; ++c) a[c] = 0.f;
  const float4* bv4 = (const float4*)bv;
  for (int p = blockIdx.x * 256 + threadIdx.x; p < P4; p += gridDim.x * 256) {
    float4 v[8];
#pragma unroll
    for (int k = 0; k < 8; ++k) v[k] = bv4[(size_t)k * P4 + p];
    int c = 0;
#pragma unroll
    for (int i = 0; i < 8; ++i)
#pragma unroll
      for (int j = i; j < 8; ++j) {
        a[c] += v[i].x * v[j].x + v[i].y * v[j].y + v[i].z * v[j].z +
                v[i].w * v[j].w;
        ++c;
      }
  }
#pragma unroll
  for (int c = 0; c < 36; ++c)
#pragma unroll
    for (int off = 32; off > 0; off >>= 1) a[c] += __shfl_down(a[c], off);
  __shared__ float red[4][36];
  const int wv = threadIdx.x >> 6;
  if ((threadIdx.x & 63) == 0)
#pragma unroll
    for (int c = 0; c < 36; ++c) red[wv][c] = a[c];
  __syncthreads();
  if (threadIdx.x < 36)
    atomicAdd(&G[threadIdx.x], red[0][threadIdx.x] + red[1][threadIdx.x] +
                                   red[2][threadIdx.x] + red[3][threadIdx.x]);
}

// ---- K4: camp[b][k] = coef[b][k] * shift_b / max(||delta||,1e-12) via Gram ----
__global__ void k_amp(const float* __restrict__ shifts_coords,
                      const float* __restrict__ batch_shifts,
                      const int* __restrict__ dirs, const float* __restrict__ G,
                      float* __restrict__ camp) {
  const int b = threadIdx.x;
  if (b < 16) {
    const int dir = dirs[b];
    float c[8];
    for (int k = 0; k < 8; ++k) c[k] = shifts_coords[dir * 8 + k];
    float n2 = 0.f;
    int idx = 0;
    for (int i = 0; i < 8; ++i)
      for (int j = i; j < 8; ++j) {
        float g = G[idx++];
        n2 += (i == j) ? c[i] * c[i] * g : 2.f * c[i] * c[j] * g;
      }
    float nrm = sqrtf(fmaxf(n2, 0.f));
    float amp = batch_shifts[b] / fmaxf(nrm, 1e-12f);
    for (int k = 0; k < 8; ++k) camp[b * 8 + k] = c[k] * amp;
  }
}

// ---- K5: modulated weights -> bf16 [b][kk][o][i]; demod table separate ----
__global__ __launch_bounds__(512) void k_weights(const float* __restrict__ weight,
                                                 const float* __restrict__ bv,
                                                 const float* __restrict__ smod,
                                                 const float* __restrict__ camp,
                                                 unsigned short* __restrict__ wgt,
                                                 float* __restrict__ demod) {
  const int o = blockIdx.x;
  const int i = threadIdx.x;
  __shared__ float cl[128];
  __shared__ float red[8][16];
  if (threadIdx.x < 128) cl[threadIdx.x] = camp[threadIdx.x];
  __syncthreads();
  const float scl = 0.014731391274719738f;  // 1/sqrt(512*9)
  float sm[16];
#pragma unroll
  for (int b = 0; b < 16; ++b) sm[b] = smod[b * 512 + i] * scl;
  float ssq[16];
#pragma unroll
  for (int b = 0; b < 16; ++b) ssq[b] = 0.f;
  const size_t base = ((size_t)o * 512 + i) * 9;
#pragma unroll
  for (int g = 0; g < 3; ++g) {
    float w[3], v[8][3];
#pragma unroll
    for (int q = 0; q < 3; ++q) w[q] = weight[base + g * 3 + q];
#pragma unroll
    for (int k = 0; k < 8; ++k)
#pragma unroll
      for (int q = 0; q < 3; ++q)
        v[k][q] = bv[(size_t)k * 2359296 + base + g * 3 + q];
#pragma unroll
    for (int b = 0; b < 16; ++b) {
#pragma unroll
      for (int q = 0; q < 3; ++q) {
        float d = w[q];
#pragma unroll
        for (int k = 0; k < 8; ++k) d = fmaf(cl[b * 8 + k], v[k][q], d);
        float wv = d * sm[b];
        ssq[b] = fmaf(wv, wv, ssq[b]);
        wgt[(((size_t)(b * 9 + g * 3 + q) * 512 + o) << 9) + i] = f2bf(wv);
      }
    }
  }
#pragma unroll
  for (int b = 0; b < 16; ++b)
#pragma unroll
    for (int off = 32; off > 0; off >>= 1) ssq[b] += __shfl_down(ssq[b], off);
  const int wv_ = threadIdx.x >> 6;
  if ((threadIdx.x & 63) == 0)
#pragma unroll
    for (int b = 0; b < 16; ++b) red[wv_][b] = ssq[b];
  __syncthreads();
  if (threadIdx.x < 16) {
    float s = 0.f;
#pragma unroll
    for (int wq = 0; wq < 8; ++wq) s += red[wq][threadIdx.x];
    demod[threadIdx.x * 512 + o] = rsqrtf(s + 1e-8f);
  }
}

// ---- K6: grouped conv, 256x128 block tile, 4 waves (2Mx2N, wave 128x64),
// BK=32, triple-buffer 3x24KB = 72KB -> 2 blocks/CU with full 43.7-FLOP/B
// geometry. R9's proven conflict-free 64B-row swizzle + no-lgkm-fence
// triple-buffer stream: per iter 12 ds_read_b128 + 6 gl_lds + 32 MFMA +
// counted vmcnt(6) + 1 barrier.
__global__ __launch_bounds__(256, 2) void k_conv(
    const unsigned short* __restrict__ xp, const unsigned short* __restrict__ wgt,
    const float* __restrict__ demod, float* __restrict__ out) {
  extern __shared__ unsigned char smem[];  // 73728 = 3 x (A 16K | B 8K)
  const int tid = threadIdx.x;  // 0..255
  const int l = tid & 63;
  const int w = tid >> 6;
  const int wr = w >> 1;  // 0..1 -> rows wr*128..+127
  const int wc = w & 1;   // 0..1 -> px  wc*64..+63

  // XCD-bijective swizzle: 1024 blocks, 128/XCD = 2 full samples per XCD
  const int bid = blockIdx.x;
  const int bz = (bid & 7) * 128 + (bid >> 3);
  const int b = bz >> 6;
  const int tt = bz & 63;
  const int o0 = (tt >> 5) << 8;  // 0 / 256
  const int tn = tt & 31;
  const int n0 = tn << 7;  // pixel base (2 rows of 64)
  const int y0 = tn << 1;

  // A staging: 4 chunks, idx=r*256+tid (0..1023): row=idx>>2, slot=idx&3,
  // pre-swizzled source chunk = slot ^ ((row>>1)&3)  [R9-verified, 0 conflicts]
  unsigned aOff[4];
#pragma unroll
  for (int r = 0; r < 4; ++r) {
    const int idx = r * 256 + tid;
    const int row = idx >> 2;
    const int sc_ = (idx & 3) ^ ((row >> 1) & 3);
    aOff[r] = ((unsigned)(o0 + row) << 10) + sc_ * 16;
  }
  // B staging: 2 chunks, idx=r*256+tid (0..511): px-row=idx>>2 (0..127)
  unsigned bOff[2];
#pragma unroll
  for (int r = 0; r < 2; ++r) {
    const int idx = r * 256 + tid;
    const int row = idx >> 2;
    const int sc_ = (idx & 3) ^ ((row >> 1) & 3);
    bOff[r] = ((unsigned)((b * 66 + y0 + (row >> 6)) * 66 + (row & 63)) << 10) +
              sc_ * 16;
  }

  const char* wgtB = (const char*)wgt + ((size_t)(b * 9) << 19);
  const char* xpc = (const char*)xp;

  auto stage = [&](unsigned char* buf, int kt) {
    const int kk = kt >> 4;  // tap
    const int is = kt & 15;  // 32-channel slice
    const int ky = kk / 3;
    const int kx = kk - ky * 3;
    const unsigned aPl = ((unsigned)kk << 19) + ((unsigned)is << 6);
    const unsigned bPl = ((unsigned)(ky * 66 + kx) << 10) + ((unsigned)is << 6);
#pragma unroll
    for (int r = 0; r < 4; ++r)
      gl_lds16(wgtB + aPl + aOff[r], buf + (r * 256 + tid) * 16);
#pragma unroll
    for (int r = 0; r < 2; ++r)
      gl_lds16(xpc + bPl + bOff[r], buf + 16384 + (r * 256 + tid) * 16);
  };

  f32x4 acc[8][4];
  const f32x4 zz = {0.f, 0.f, 0.f, 0.f};
#pragma unroll
  for (int mi = 0; mi < 8; ++mi)
#pragma unroll
    for (int ni = 0; ni < 4; ++ni) acc[mi][ni] = zz;
  bf16x8 af[8], bf[4];

  const int lq = l & 15;
  const int ls = l >> 4;

  unsigned char* p0 = smem;
  unsigned char* p1 = smem + 24576;
  unsigned char* p2 = smem + 49152;
  stage(p0, 0);
  stage(p1, 1);
  vm_wait<6>();
  __builtin_amdgcn_s_barrier();
  __builtin_amdgcn_sched_barrier(0);

#pragma unroll 1
  for (int kt = 0; kt < 144; ++kt) {
    const unsigned char* lA = p0;
    const unsigned char* lB = p0 + 16384;
#pragma unroll
    for (int ni = 0; ni < 4; ++ni) {
      const int row = wc * 64 + ni * 16 + lq;
      bf[ni] = *(const bf16x8*)(lB + row * 64 + ((ls ^ ((row >> 1) & 3)) << 4));
    }
#pragma unroll
    for (int mi = 0; mi < 8; ++mi) {
      const int row = wr * 128 + mi * 16 + lq;
      af[mi] = *(const bf16x8*)(lA + row * 64 + ((ls ^ ((row >> 1) & 3)) << 4));
    }
    if (kt <= 141) stage(p2, kt + 2);  // p2 held kt-1, consumed pre-barrier
    __builtin_amdgcn_s_setprio(1);
#pragma unroll
    for (int mi = 0; mi < 8; ++mi)
#pragma unroll
      for (int ni = 0; ni < 4; ++ni)
        acc[mi][ni] = __builtin_amdgcn_mfma_f32_16x16x32_bf16(
            af[mi], bf[ni], acc[mi][ni], 0, 0, 0);
    __builtin_amdgcn_s_setprio(0);
    __builtin_amdgcn_sched_barrier(0);
    if (kt <= 141) vm_wait<6>();        // kt+1's 6 done; kt+2's 6 in flight
    else if (kt == 142) vm_wait<0>();
    if (kt <= 142) {
      __builtin_amdgcn_s_barrier();
      __builtin_amdgcn_sched_barrier(0);
    }
    unsigned char* tmp = p0; p0 = p1; p1 = p2; p2 = tmp;
  }

  float* outb = out + (size_t)(b * 512 + o0) * 4096 + n0;
#pragma unroll
  for (int mi = 0; mi < 8; ++mi) {
    const int orow = wr * 128 + mi * 16 + ls * 4;
    float dm[4];
#pragma unroll
    for (int r = 0; r < 4; ++r) dm[r] = demod[b * 512 + o0 + orow + r];
#pragma unroll
    for (int ni = 0; ni < 4; ++ni) {
      const int pix = wc * 64 + ni * 16 + lq;
#pragma unroll
      for (int r = 0; r < 4; ++r)
        outb[(size_t)(orow + r) * 4096 + pix] = acc[mi][ni][r] * dm[r];
    }
  }
}

extern "C" void kernel_launch(void* const* d_in, const int* in_sizes, int n_in,
                              void* d_out, int out_size, void* d_ws,
                              size_t ws_size, hipStream_t stream) {
  const float* x      = (const float*)d_in[0];
  const float* style  = (const float*)d_in[1];
  const float* weight = (const float*)d_in[2];
  const float* mod_w  = (const float*)d_in[3];
  const float* mod_b  = (const float*)d_in[4];
  const float* bv     = (const float*)d_in[5];
  const float* sc     = (const float*)d_in[6];
  const float* bsh    = (const float*)d_in[7];
  const int*   bdir   = (const int*)d_in[8];
  float* out = (float*)d_out;

  char* ws = (char*)d_ws;
  unsigned short* xp  = (unsigned short*)(ws);
  unsigned short* wgt = (unsigned short*)(ws + 71368704);
  float* G     = (float*)(ws + 146866176);
  float* camp  = (float*)(ws + 146866432);
  float* smod  = (float*)(ws + 146866944);
  float* demod = (float*)(ws + 146899712);

  hipFuncSetAttribute((const void*)k_conv,
                      hipFuncAttributeMaxDynamicSharedMemorySize, 73728);

  hipMemsetAsync(G, 0, 256, stream);
  k_pad<<<8192, 256, 0, stream>>>(x, xp);
  k_mod<<<16, 256, 0, stream>>>(style, mod_w, mod_b, smod);
  k_gram<<<1024, 256, 0, stream>>>(bv, G);
  k_amp<<<1, 64, 0, stream>>>(sc, bsh, bdir, G, camp);
  k_weights<<<512, 512, 0, stream>>>(weight, bv, smod, camp, wgt, demod);
  k_conv<<<1024, 256, 73728, stream>>>(xp, wgt, demod, out);
}

// Round 11
// 419.225 us; speedup vs baseline: 1.0794x; 1.0616x over previous
//
#include <hip/hip_runtime.h>

// Sizes (fixed): B=16, CIN=512, COUT=512, K=3, H=W=64, STYLE=512, BASIS=8, DIRS=8
// Workspace layout (bytes):
//  xp   (NHWC padded bf16 [16][66][66][512])  @ 0          : 71,368,704
//  wgt  (bf16 [16][9][512][512], NO demod)    @ 71,368,704 : 75,497,472
//  G    (36 floats, padded)                   @ 146,866,176: 256
//  camp ([16][8] f32)                         @ 146,866,432: 512
//  smod ([16][512] f32)                       @ 146,866,944: 32,768
//  demod([16][512] f32)                       @ 146,899,712: 32,768

typedef __attribute__((ext_vector_type(8))) short bf16x8;
typedef __attribute__((ext_vector_type(4))) float f32x4;

__device__ __forceinline__ unsigned short f2bf(float f) {
  unsigned u = __float_as_uint(f);
  return (unsigned short)((u + 0x7FFFu + ((u >> 16) & 1u)) >> 16);
}

__device__ __forceinline__ void gl_lds16(const void* g, void* l) {
  __builtin_amdgcn_global_load_lds(
      (const __attribute__((address_space(1))) void*)g,
      (__attribute__((address_space(3))) void*)l, 16, 0, 0);
}

template <int N> __device__ __forceinline__ void vm_wait() {
  if constexpr (N == 9) asm volatile("s_waitcnt vmcnt(9)" ::: "memory");
  else if constexpr (N == 2) asm volatile("s_waitcnt vmcnt(2)" ::: "memory");
  else if constexpr (N == 0) asm volatile("s_waitcnt vmcnt(0)" ::: "memory");
}

// ---- K1: pad + NCHW f32 -> NHWC bf16, borders zeroed in-kernel ----
__global__ __launch_bounds__(256) void k_pad(const float* __restrict__ x,
                                             unsigned short* __restrict__ xp) {
  const int bx = blockIdx.x;
  const int b   = bx >> 9;
  const int rem = bx & 511;
  const int y   = rem >> 3;
  const int cb  = rem & 7;
  const int t = threadIdx.x;
  __shared__ float tile[64][65];
  const float* src = x + ((size_t)(b * 512 + cb * 64) * 4096) + y * 64;
#pragma unroll
  for (int r = 0; r < 4; ++r) {
    int idx = r * 256 + t;
    int ch = idx >> 4;
    int xq = (idx & 15) << 2;
    float4 v = *(const float4*)(src + (size_t)ch * 4096 + xq);
    tile[ch][xq + 0] = v.x; tile[ch][xq + 1] = v.y;
    tile[ch][xq + 2] = v.z; tile[ch][xq + 3] = v.w;
  }
  const uint4 z4 = {0u, 0u, 0u, 0u};
  if (t < 16) {
    const int side = t >> 3;
    const int lo = (t & 7) * 8;
    unsigned short* p =
        xp + (((size_t)(b * 66 + y + 1) * 66 + side * 65) * 512 + cb * 64 + lo);
    *(uint4*)p = z4;
  }
  if (y == 0 || y == 63) {
    const int row = (y == 0) ? 0 : 65;
    for (int idx = t; idx < 528; idx += 256) {
      const int c = idx >> 3;
      const int lo = (idx & 7) * 8;
      unsigned short* p =
          xp + (((size_t)(b * 66 + row) * 66 + c) * 512 + cb * 64 + lo);
      *(uint4*)p = z4;
    }
  }
  __syncthreads();
  const int col = t >> 2;
  const int q = t & 3;
  union { unsigned short u16[16]; uint4 v[2]; } pk;
#pragma unroll
  for (int j = 0; j < 16; ++j) pk.u16[j] = f2bf(tile[q * 16 + j][col]);
  unsigned short* dst =
      xp + (((size_t)(b * 66 + y + 1) * 66 + col + 1) * 512 + cb * 64 + q * 16);
  *(uint4*)dst = pk.v[0];
  *(uint4*)(dst + 8) = pk.v[1];
}

// ---- K2: s[b][i] = style[b] . mod_w[i] + mod_b[i] ----
__global__ __launch_bounds__(256) void k_mod(const float* __restrict__ style,
                                             const float* __restrict__ mod_w,
                                             const float* __restrict__ mod_b,
                                             float* __restrict__ smod) {
  const int b = blockIdx.x;
  __shared__ float st[512];
  for (int d = threadIdx.x; d < 512; d += 256) st[d] = style[b * 512 + d];
  __syncthreads();
  for (int i = threadIdx.x; i < 512; i += 256) {
    const float* wr = mod_w + (size_t)i * 512;
    float acc = 0.f;
#pragma unroll 4
    for (int d = 0; d < 512; d += 4) {
      float4 wv = *(const float4*)(wr + d);
      acc += wv.x * st[d] + wv.y * st[d + 1] + wv.z * st[d + 2] + wv.w * st[d + 3];
    }
    smod[b * 512 + i] = acc + mod_b[i];
  }
}

// ---- K3: Gram matrix of the 8 basis vectors (upper-tri, 36 entries) ----
__global__ __launch_bounds__(256, 3) void k_gram(const float* __restrict__ bv,
                                                 float* __restrict__ G) {
  const int P4 = 589824;  // (512*512*9)/4
  float a[36];
#pragma unroll
  for (int c = 0; c < 36; ++c) a[c] = 0.f;
  const float4* bv4 = (const float4*)bv;
  for (int p = blockIdx.x * 256 + threadIdx.x; p < P4; p += gridDim.x * 256) {
    float4 v[8];
#pragma unroll
    for (int k = 0; k < 8; ++k) v[k] = bv4[(size_t)k * P4 + p];
    int c = 0;
#pragma unroll
    for (int i = 0; i < 8; ++i)
#pragma unroll
      for (int j = i; j < 8; ++j) {
        a[c] += v[i].x * v[j].x + v[i].y * v[j].y + v[i].z * v[j].z +
                v[i].w * v[j].w;
        ++c;
      }
  }
#pragma unroll
  for (int c = 0; c < 36; ++c)
#pragma unroll
    for (int off = 32; off > 0; off >>= 1) a[c] += __shfl_down(a[c], off);
  __shared__ float red[4][36];
  const int wv = threadIdx.x >> 6;
  if ((threadIdx.x & 63) == 0)
#pragma unroll
    for (int c = 0; c < 36; ++c) red[wv][c] = a[c];
  __syncthreads();
  if (threadIdx.x < 36)
    atomicAdd(&G[threadIdx.x], red[0][threadIdx.x] + red[1][threadIdx.x] +
                                   red[2][threadIdx.x] + red[3][threadIdx.x]);
}

// ---- K4: camp[b][k] = coef[b][k] * shift_b / max(||delta||,1e-12) via Gram ----
__global__ void k_amp(const float* __restrict__ shifts_coords,
                      const float* __restrict__ batch_shifts,
                      const int* __restrict__ dirs, const float* __restrict__ G,
                      float* __restrict__ camp) {
  const int b = threadIdx.x;
  if (b < 16) {
    const int dir = dirs[b];
    float c[8];
    for (int k = 0; k < 8; ++k) c[k] = shifts_coords[dir * 8 + k];
    float n2 = 0.f;
    int idx = 0;
    for (int i = 0; i < 8; ++i)
      for (int j = i; j < 8; ++j) {
        float g = G[idx++];
        n2 += (i == j) ? c[i] * c[i] * g : 2.f * c[i] * c[j] * g;
      }
    float nrm = sqrtf(fmaxf(n2, 0.f));
    float amp = batch_shifts[b] / fmaxf(nrm, 1e-12f);
    for (int k = 0; k < 8; ++k) camp[b * 8 + k] = c[k] * amp;
  }
}

// ---- K5: modulated weights -> bf16 [b][kk][o][i]; demod table separate ----
__global__ __launch_bounds__(512) void k_weights(const float* __restrict__ weight,
                                                 const float* __restrict__ bv,
                                                 const float* __restrict__ smod,
                                                 const float* __restrict__ camp,
                                                 unsigned short* __restrict__ wgt,
                                                 float* __restrict__ demod) {
  const int o = blockIdx.x;
  const int i = threadIdx.x;
  __shared__ float cl[128];
  __shared__ float red[8][16];
  if (threadIdx.x < 128) cl[threadIdx.x] = camp[threadIdx.x];
  __syncthreads();
  const float scl = 0.014731391274719738f;  // 1/sqrt(512*9)
  float sm[16];
#pragma unroll
  for (int b = 0; b < 16; ++b) sm[b] = smod[b * 512 + i] * scl;
  float ssq[16];
#pragma unroll
  for (int b = 0; b < 16; ++b) ssq[b] = 0.f;
  const size_t base = ((size_t)o * 512 + i) * 9;
#pragma unroll
  for (int g = 0; g < 3; ++g) {
    float w[3], v[8][3];
#pragma unroll
    for (int q = 0; q < 3; ++q) w[q] = weight[base + g * 3 + q];
#pragma unroll
    for (int k = 0; k < 8; ++k)
#pragma unroll
      for (int q = 0; q < 3; ++q)
        v[k][q] = bv[(size_t)k * 2359296 + base + g * 3 + q];
#pragma unroll
    for (int b = 0; b < 16; ++b) {
#pragma unroll
      for (int q = 0; q < 3; ++q) {
        float d = w[q];
#pragma unroll
        for (int k = 0; k < 8; ++k) d = fmaf(cl[b * 8 + k], v[k][q], d);
        float wv = d * sm[b];
        ssq[b] = fmaf(wv, wv, ssq[b]);
        wgt[(((size_t)(b * 9 + g * 3 + q) * 512 + o) << 9) + i] = f2bf(wv);
      }
    }
  }
#pragma unroll
  for (int b = 0; b < 16; ++b)
#pragma unroll
    for (int off = 32; off > 0; off >>= 1) ssq[b] += __shfl_down(ssq[b], off);
  const int wv_ = threadIdx.x >> 6;
  if ((threadIdx.x & 63) == 0)
#pragma unroll
    for (int b = 0; b < 16; ++b) red[wv_][b] = ssq[b];
  __syncthreads();
  if (threadIdx.x < 16) {
    float s = 0.f;
#pragma unroll
    for (int wq = 0; wq < 8; ++wq) s += red[wq][threadIdx.x];
    demod[threadIdx.x * 512 + o] = rsqrtf(s + 1e-8f);
  }
}

// ---- K6: grouped conv, block 128o x 256px, 4 waves (wave 64o x 128px).
// B staged ONCE per 32-ch slice as a 6x68-row halo in LDS; all 9 taps read
// it at shifted rows (9x less B L2 traffic). A triple-buffered per (cs,tap).
// 2 blocks/CU (75KB LDS, ~230 regs) -> cross-block stall cover.
// vmcnt ledger: halo prefetch (7 loads, uniform/wave) at kk==0; waits:
// kk<2 -> vmcnt(9) [leave A(t+2)2 + halo7], else vmcnt(2) [leave A(t+2)].
__global__ __launch_bounds__(256, 2) void k_conv(
    const unsigned short* __restrict__ xp, const unsigned short* __restrict__ wgt,
    const float* __restrict__ demod, float* __restrict__ out) {
  extern __shared__ unsigned char smem[];  // 76800 = A:3x8192 | halo:2x26112
  const int tid = threadIdx.x;  // 0..255
  const int l = tid & 63;
  const int w = tid >> 6;
  const int wr = w >> 1;  // 0..1 -> o rows wr*64..+63
  const int wc = w & 1;   // 0..1 -> px wc*128..+127

  // XCD-bijective swizzle: 1024 blocks, 128/XCD = 2 full samples per XCD
  const int bid = blockIdx.x;
  const int bz = (bid & 7) * 128 + (bid >> 3);
  const int b = bz >> 6;
  const int ot = (bz >> 4) & 3;
  const int tn = bz & 15;
  const int o0 = ot << 7;
  const int tn4 = tn << 2;

  // A staging: 2 chunks/thread, slice = 128 rows x 64B (R9-proven swizzle)
  unsigned aOff[2];
#pragma unroll
  for (int r = 0; r < 2; ++r) {
    const int idx = r * 256 + tid;
    const int row = idx >> 2;
    const int sl = (idx & 3) ^ ((row >> 1) & 3);
    aOff[r] = ((unsigned)(o0 + row) << 10) + sl * 16;
  }
  // Halo staging: 1632 chunks (408 rows x 64B), 7 chunks/thread uniform
  // (last iter overlaps: wave0 covers 1536-1599, waves1-3 cover 1568-1631).
  size_t hsrc[7];
  int hdst[7];
#pragma unroll
  for (int it = 0; it < 7; ++it) {
    int h;
    if (it < 6) h = it * 256 + tid;
    else h = ((w == 0) ? 1536 : 1568) + l;
    const int r = h >> 2;
    const int sl = (h & 3) ^ ((r >> 1) & 3);
    const int hy = r / 68;
    const int hx = r - hy * 68;
    hsrc[it] = ((size_t)((b * 66 + tn4 + hy) * 66 + hx) << 10) + sl * 16;
    hdst[it] = h * 16;
  }

  const char* wgtB = (const char*)wgt + ((size_t)(b * 9) << 19);
  const char* xpc = (const char*)xp;

  unsigned char* pA0 = smem;
  unsigned char* pA1 = smem + 8192;
  unsigned char* pA2 = smem + 16384;
  unsigned char* hb0 = smem + 24576;
  unsigned char* hb1 = smem + 50688;

  auto stageA = [&](unsigned char* buf, int s) {
    const int c2 = s / 9;
    const int k2 = s - c2 * 9;
    const char* base = wgtB + ((size_t)k2 << 19) + c2 * 64;
#pragma unroll
    for (int r = 0; r < 2; ++r)
      gl_lds16(base + aOff[r], buf + (r * 256 + tid) * 16);
  };
  auto stageH = [&](unsigned char* hb, int c2) {
#pragma unroll
    for (int it = 0; it < 7; ++it)
      gl_lds16(xpc + hsrc[it] + c2 * 64, hb + hdst[it]);
  };

  f32x4 acc[4][8];
  const f32x4 zz = {0.f, 0.f, 0.f, 0.f};
#pragma unroll
  for (int mi = 0; mi < 4; ++mi)
#pragma unroll
    for (int ni = 0; ni < 8; ++ni) acc[mi][ni] = zz;
  bf16x8 af[4], bf[8];

  const int lq = l & 15;
  const int ls = l >> 4;
  int rB[8];
#pragma unroll
  for (int ni = 0; ni < 8; ++ni) {
    const int p = wc * 128 + ni * 16 + lq;
    rB[ni] = (p >> 6) * 68 + (p & 63);
  }
  unsigned aRd[4];
#pragma unroll
  for (int mi = 0; mi < 4; ++mi) {
    const int r = wr * 64 + mi * 16 + lq;
    aRd[mi] = r * 64 + ((ls ^ ((r >> 1) & 3)) << 4);
  }

  // prologue: halo(cs0), A(0), A(1); wait halo+A(0) (leave A(1) in flight)
  stageH(hb0, 0);
  stageA(pA0, 0);
  stageA(pA1, 1);
  vm_wait<2>();
  __builtin_amdgcn_s_barrier();
  __builtin_amdgcn_sched_barrier(0);

  int cs = 0, kk = 0;
#pragma unroll 1
  for (int step = 0; step < 144; ++step) {
    const unsigned char* hb = (cs & 1) ? hb1 : hb0;
    const int ky = kk / 3;
    const int rofs = (ky * 68) + (kk - ky * 3);
#pragma unroll
    for (int ni = 0; ni < 8; ++ni) {
      const int r = rB[ni] + rofs;
      bf[ni] = *(const bf16x8*)(hb + r * 64 + ((ls ^ ((r >> 1) & 3)) << 4));
    }
#pragma unroll
    for (int mi = 0; mi < 4; ++mi)
      af[mi] = *(const bf16x8*)(pA0 + aRd[mi]);
    if (step <= 141) stageA(pA2, step + 2);
    if (kk == 0 && cs < 15) stageH((cs & 1) ? hb0 : hb1, cs + 1);
    __builtin_amdgcn_s_setprio(1);
#pragma unroll
    for (int mi = 0; mi < 4; ++mi)
#pragma unroll
      for (int ni = 0; ni < 8; ++ni)
        acc[mi][ni] = __builtin_amdgcn_mfma_f32_16x16x32_bf16(
            af[mi], bf[ni], acc[mi][ni], 0, 0, 0);
    __builtin_amdgcn_s_setprio(0);
    __builtin_amdgcn_sched_barrier(0);
    if (step == 142) vm_wait<0>();
    else if (step <= 141) {
      if (cs < 15 && kk < 2) vm_wait<9>();
      else vm_wait<2>();
    }
    if (step <= 142) {
      __builtin_amdgcn_s_barrier();
      __builtin_amdgcn_sched_barrier(0);
    }
    unsigned char* tmp = pA0; pA0 = pA1; pA1 = pA2; pA2 = tmp;
    if (++kk == 9) { kk = 0; ++cs; }
  }

  float* outb = out + (size_t)(b * 512 + o0) * 4096 + tn * 256;
#pragma unroll
  for (int mi = 0; mi < 4; ++mi) {
    const int orow = wr * 64 + mi * 16 + ls * 4;
    float dm[4];
#pragma unroll
    for (int r = 0; r < 4; ++r) dm[r] = demod[b * 512 + o0 + orow + r];
#pragma unroll
    for (int ni = 0; ni < 8; ++ni) {
      const int pix = wc * 128 + ni * 16 + lq;
#pragma unroll
      for (int r = 0; r < 4; ++r)
        outb[(size_t)(orow + r) * 4096 + pix] = acc[mi][ni][r] * dm[r];
    }
  }
}

extern "C" void kernel_launch(void* const* d_in, const int* in_sizes, int n_in,
                              void* d_out, int out_size, void* d_ws,
                              size_t ws_size, hipStream_t stream) {
  const float* x      = (const float*)d_in[0];
  const float* style  = (const float*)d_in[1];
  const float* weight = (const float*)d_in[2];
  const float* mod_w  = (const float*)d_in[3];
  const float* mod_b  = (const float*)d_in[4];
  const float* bv     = (const float*)d_in[5];
  const float* sc     = (const float*)d_in[6];
  const float* bsh    = (const float*)d_in[7];
  const int*   bdir   = (const int*)d_in[8];
  float* out = (float*)d_out;

  char* ws = (char*)d_ws;
  unsigned short* xp  = (unsigned short*)(ws);
  unsigned short* wgt = (unsigned short*)(ws + 71368704);
  float* G     = (float*)(ws + 146866176);
  float* camp  = (float*)(ws + 146866432);
  float* smod  = (float*)(ws + 146866944);
  float* demod = (float*)(ws + 146899712);

  hipFuncSetAttribute((const void*)k_conv,
                      hipFuncAttributeMaxDynamicSharedMemorySize, 76800);

  hipMemsetAsync(G, 0, 256, stream);
  k_pad<<<8192, 256, 0, stream>>>(x, xp);
  k_mod<<<16, 256, 0, stream>>>(style, mod_w, mod_b, smod);
  k_gram<<<1024, 256, 0, stream>>>(bv, G);
  k_amp<<<1, 64, 0, stream>>>(sc, bsh, bdir, G, camp);
  k_weights<<<512, 512, 0, stream>>>(weight, bv, smod, camp, wgt, demod);
  k_conv<<<1024, 256, 76800, stream>>>(xp, wgt, demod, out);
}